// Round 6
// baseline (2563.136 us; speedup 1.0000x reference)
//
#include <hip/hip_runtime.h>
#include <hip/hip_bf16.h>

// Problem constants
#define Bb    2
#define Nn    1024
#define NCTXc 2048
#define DIMd  1024
#define Hh    16
#define DHd   64
#define NMEM  16
#define Jv    (NMEM + NCTXc)   // 2064 valid kv rows
#define JP    2112             // padded to multiple of 64
#define IC    256              // i-chunk rows (S materialized per (b, i-chunk))
#define L2E   1.44269504088896f

typedef _Float16 f16;
typedef _Float16 half8 __attribute__((ext_vector_type(8)));
typedef float    f32x4 __attribute__((ext_vector_type(4)));

__device__ __forceinline__ float bf2f(unsigned short u){
  union { unsigned int i; float f; } v; v.i = ((unsigned)u) << 16; return v.f;
}
// sanitize: NaN -> 0, clamp to f16-safe range (identity on well-formed inputs)
__device__ __forceinline__ float fin(float v){
  v = (v == v) ? v : 0.f;
  return fminf(fmaxf(v, -65504.f), 65504.f);
}
// dtype-flag-dispatched input read. isf32: 1 = buffer holds float32, 0 = bf16.
__device__ __forceinline__ float ldin(const void* p, long i, int isf32){
  return isf32 ? ((const float*)p)[i] : bf2f(((const unsigned short*)p)[i]);
}
__device__ __forceinline__ half8 h8zero(){
  half8 v;
  #pragma unroll
  for (int j = 0; j < 8; j++) v[j] = (f16)0.f;
  return v;
}

// ---------------- dtype probe: which interpretation of d_in[0] is sane? ----------------
__global__ void detect_dtype(const void* __restrict__ p, int* __restrict__ flag, int n){
  const unsigned short* ub = (const unsigned short*)p;
  const float* fp = (const float*)p;
  int t = threadIdx.x;
  float bb = 0.f, bf = 0.f;
  for (int i = t; i < n; i += 64){
    float vb = bf2f(ub[i]);
    if (!(vb == vb) || fabsf(vb) > 1000.f) bb += 1.f;
    float vf = fp[i];
    if (!(vf == vf) || fabsf(vf) > 1000.f) bf += 1.f;
  }
  #pragma unroll
  for (int off = 32; off; off >>= 1){ bb += __shfl_xor(bb, off); bf += __shfl_xor(bf, off); }
  if (t == 0) *flag = (bf < bb) ? 1 : 0;
}

// ---------------- any-dtype -> f16 convert (sanitized) ----------------
__global__ __launch_bounds__(256) void cvt_any(const void* __restrict__ in, f16* __restrict__ out,
                                               long n, const int* __restrict__ flag){
  int isf = *flag;
  long stride = (long)gridDim.x * 256;
  for (long i = (long)blockIdx.x * 256 + threadIdx.x; i < n; i += stride)
    out[i] = (f16)fin(ldin(in, i, isf));
}

// ---------------- any-dtype -> f32 convert (sanitized, small params) ----------------
__global__ __launch_bounds__(256) void cvt32_any(const void* __restrict__ in, float* __restrict__ out,
                                                 long n, const int* __restrict__ flag){
  int isf = *flag;
  long stride = (long)gridDim.x * 256;
  for (long i = (long)blockIdx.x * 256 + threadIdx.x; i < n; i += stride)
    out[i] = fin(ldin(in, i, isf));
}

// ---------------- transpose + convert: out[c][r] = in[r][c] ----------------
__global__ __launch_bounds__(256) void transpose_any(const void* __restrict__ in,
                                                     f16* __restrict__ out,
                                                     int Cc, long ldo,
                                                     const int* __restrict__ flag){
  __shared__ f16 tile[32][33];
  int isf = *flag;
  int r0 = blockIdx.y * 32, c0 = blockIdx.x * 32;
  int tr = threadIdx.x >> 5, tc = threadIdx.x & 31;
  #pragma unroll
  for (int k = 0; k < 4; k++){
    int r = tr + k * 8;
    tile[r][tc] = (f16)fin(ldin(in, (long)(r0 + r) * Cc + c0 + tc, isf));
  }
  __syncthreads();
  #pragma unroll
  for (int k = 0; k < 4; k++){
    int r = tr + k * 8;
    out[(long)(c0 + r) * ldo + r0 + tc] = tile[tc][r];
  }
}

// ---------------- generic batched GEMM: C[m][n] = sum_k A[m][k]*Bt[n][k] ----------------
__global__ __launch_bounds__(256) void gemm_bt(
    const f16* __restrict__ A, const f16* __restrict__ Bt, f16* __restrict__ C,
    int K, long lda, long ldb, long ldc,
    long sAh, long sBh, long sCh)
{
  int zh = blockIdx.z;
  A  += (long)zh * sAh;
  Bt += (long)zh * sBh;
  C  += (long)zh * sCh;
  long m0 = (long)blockIdx.y * 64, n0 = (long)blockIdx.x * 64;

  __shared__ f16 As[64][40];
  __shared__ f16 Bs[64][40];
  int t = threadIdx.x;
  int wave = t >> 6, lane = t & 63;
  int wm = (wave >> 1) * 32, wn = (wave & 1) * 32;
  int fr = lane & 15, fq = lane >> 4;
  int srow = t >> 2, scol = (t & 3) * 8;

  f32x4 acc[2][2];
  #pragma unroll
  for (int a = 0; a < 2; a++)
    #pragma unroll
    for (int b = 0; b < 2; b++) acc[a][b] = (f32x4){0.f, 0.f, 0.f, 0.f};

  for (int k0 = 0; k0 < K; k0 += 32){
    half8 avv = *(const half8*)(A  + (m0 + srow) * lda + k0 + scol);
    half8 bvv = *(const half8*)(Bt + (n0 + srow) * ldb + k0 + scol);
    __syncthreads();
    *(half8*)&As[srow][scol] = avv;
    *(half8*)&Bs[srow][scol] = bvv;
    __syncthreads();
    #pragma unroll
    for (int ti = 0; ti < 2; ti++){
      half8 af = *(const half8*)&As[wm + 16 * ti + fr][fq * 8];
      #pragma unroll
      for (int tj = 0; tj < 2; tj++){
        half8 bf = *(const half8*)&Bs[wn + 16 * tj + fr][fq * 8];
        acc[ti][tj] = __builtin_amdgcn_mfma_f32_16x16x32_f16(af, bf, acc[ti][tj], 0, 0, 0);
      }
    }
  }
  #pragma unroll
  for (int ti = 0; ti < 2; ti++)
    #pragma unroll
    for (int tj = 0; tj < 2; tj++)
      #pragma unroll
      for (int r = 0; r < 4; r++){
        long row = m0 + wm + 16 * ti + fq * 4 + r;
        long col = n0 + wn + 16 * tj + fr;
        C[row * ldc + col] = (f16)acc[ti][tj][r];
      }
}

// ---------------- final GEMM with dtype-dispatched output store ----------------
__global__ __launch_bounds__(256) void gemm_bt_dyn(
    const f16* __restrict__ A, const f16* __restrict__ Bt, void* __restrict__ C,
    int K, long lda, long ldb, long ldc, const int* __restrict__ flag)
{
  int isf = *flag;
  long m0 = (long)blockIdx.y * 64, n0 = (long)blockIdx.x * 64;

  __shared__ f16 As[64][40];
  __shared__ f16 Bs[64][40];
  int t = threadIdx.x;
  int wave = t >> 6, lane = t & 63;
  int wm = (wave >> 1) * 32, wn = (wave & 1) * 32;
  int fr = lane & 15, fq = lane >> 4;
  int srow = t >> 2, scol = (t & 3) * 8;

  f32x4 acc[2][2];
  #pragma unroll
  for (int a = 0; a < 2; a++)
    #pragma unroll
    for (int b = 0; b < 2; b++) acc[a][b] = (f32x4){0.f, 0.f, 0.f, 0.f};

  for (int k0 = 0; k0 < K; k0 += 32){
    half8 avv = *(const half8*)(A  + (m0 + srow) * lda + k0 + scol);
    half8 bvv = *(const half8*)(Bt + (n0 + srow) * ldb + k0 + scol);
    __syncthreads();
    *(half8*)&As[srow][scol] = avv;
    *(half8*)&Bs[srow][scol] = bvv;
    __syncthreads();
    #pragma unroll
    for (int ti = 0; ti < 2; ti++){
      half8 af = *(const half8*)&As[wm + 16 * ti + fr][fq * 8];
      #pragma unroll
      for (int tj = 0; tj < 2; tj++){
        half8 bf = *(const half8*)&Bs[wn + 16 * tj + fr][fq * 8];
        acc[ti][tj] = __builtin_amdgcn_mfma_f32_16x16x32_f16(af, bf, acc[ti][tj], 0, 0, 0);
      }
    }
  }
  #pragma unroll
  for (int ti = 0; ti < 2; ti++)
    #pragma unroll
    for (int tj = 0; tj < 2; tj++)
      #pragma unroll
      for (int r = 0; r < 4; r++){
        long row = m0 + wm + 16 * ti + fq * 4 + r;
        long col = n0 + wn + 16 * tj + fr;
        float v = acc[ti][tj][r];
        if (isf) ((float*)C)[row * ldc + col] = v;
        else     ((__hip_bfloat16*)C)[row * ldc + col] = __float2bfloat16(v);
      }
}

// ---------------- q: l2norm per head + fold per-head scale ----------------
__global__ __launch_bounds__(256) void qn_build(const f16* __restrict__ qp, f16* __restrict__ qn,
                                                const float* __restrict__ scale_p){
  int row = blockIdx.x;                 // 0..B*N-1
  int wave = threadIdx.x >> 6, lane = threadIdx.x & 63;
  #pragma unroll
  for (int hh = 0; hh < 4; hh++){
    int h = wave * 4 + hh;
    float v = fin((float)qp[(long)row * 1024 + h * 64 + lane]);
    float ss = v * v;
    #pragma unroll
    for (int off = 32; off; off >>= 1) ss += __shfl_xor(ss, off);
    float sc = 1.0f / fmaxf(__expf(scale_p[h]), 0.01f);
    float o = v / fmaxf(sqrtf(ss), 1e-12f) * sc;
    qn[(long)row * 1024 + h * 64 + lane] = (f16)o;
  }
}

// ---------------- k buffer: mem_k prepended, l2norm, zero pad ----------------
__global__ __launch_bounds__(256) void kbuf_build(const f16* __restrict__ kp,
                                                  const f16* __restrict__ mem_k,
                                                  f16* __restrict__ kbuf){
  int id = blockIdx.x * 4 + (threadIdx.x >> 6);  // (b*JP + j)*16 + h
  int lane = threadIdx.x & 63;
  int h = id & 15; int bj = id >> 4; int j = bj % JP; int b = bj / JP;
  float v;
  if (j < NMEM)              v = (float)mem_k[(h * NMEM + j) * 64 + lane];
  else if (j < NMEM + NCTXc) v = fin((float)kp[((long)b * NCTXc + (j - NMEM)) * 1024 + h * 64 + lane]);
  else                       v = 0.f;
  float ss = v * v;
  #pragma unroll
  for (int off = 32; off; off >>= 1) ss += __shfl_xor(ss, off);
  float o = v / fmaxf(sqrtf(ss), 1e-12f);
  kbuf[((long)b * JP + j) * 1024 + h * 64 + lane] = (f16)o;
}

// ---------------- v buffer, transposed per head: vt[(b,h)][d][j] ----------------
__global__ __launch_bounds__(256) void vt_build(const f16* __restrict__ vp,
                                                const f16* __restrict__ mem_v,
                                                f16* __restrict__ vt){
  __shared__ f16 tile[64][72];
  int id = blockIdx.x;
  int jt = id % (JP / 64); int h = (id / (JP / 64)) & 15; int b = id / (16 * (JP / 64));
  int j0 = jt * 64;
  int t = threadIdx.x;
  #pragma unroll
  for (int rep = 0; rep < 2; rep++){
    int idx = t + rep * 256;
    int jj = idx >> 3, c8 = (idx & 7) * 8;
    int j = j0 + jj;
    half8 v;
    if (j < NMEM){
      v = *(const half8*)(mem_v + (h * NMEM + j) * 64 + c8);
    } else if (j < NMEM + NCTXc){
      v = *(const half8*)(vp + ((long)b * NCTXc + (j - NMEM)) * 1024 + h * 64 + c8);
      #pragma unroll
      for (int k = 0; k < 8; k++) v[k] = (f16)fin((float)v[k]);
    } else {
      v = h8zero();
    }
    *(half8*)&tile[jj][c8] = v;
  }
  __syncthreads();
  #pragma unroll
  for (int rep = 0; rep < 2; rep++){
    int idx = t + rep * 256;
    int d = idx >> 3, j8 = (idx & 7) * 8;
    half8 o;
    #pragma unroll
    for (int k = 0; k < 8; k++) o[k] = tile[j8 + k][d];
    *(half8*)(vt + (((long)(b * 16 + h) * 64 + d) * JP) + j0 + j8) = o;
  }
}

// ---------------- fused pre-mix + softmax + post-mix, pure VALU, in-place ----------------
// One block per i-row of the chunk. Sc layout [h][i][j], head stride HS = IC*JP.
__global__ __launch_bounds__(256) void softmax_mix_valu(
    f16* __restrict__ Sc,
    const float* __restrict__ th_pre,
    const float* __restrict__ th_post,
    const float* __restrict__ hs)
{
  const long HS = (long)IC * JP;
  __shared__ float Apre[16][20];
  __shared__ float Cpost[16][20];
  __shared__ float msh[4][16], lsh[4][16];
  int t = threadIdx.x, wave = t >> 6, lane = t & 63;
  f16* Srow = Sc + (long)blockIdx.x * JP;

  { int g = t >> 4, h = t & 15; Apre[g][h] = th_pre[g * 16 + h]; }
  __syncthreads();

  float m[16], l[16];
  #pragma unroll
  for (int g = 0; g < 16; g++){ m[g] = -1e30f; l[g] = 0.f; }

  // sweep 1
  for (int it = 0; it < 9; it++){
    int col = it * 256 + t;
    if (col < Jv){
      float s[16];
      #pragma unroll
      for (int h = 0; h < 16; h++) s[h] = fin((float)Srow[(long)h * HS + col]);
      #pragma unroll
      for (int g = 0; g < 16; g++){
        float4 a0 = *(const float4*)&Apre[g][0];
        float4 a1 = *(const float4*)&Apre[g][4];
        float4 a2 = *(const float4*)&Apre[g][8];
        float4 a3 = *(const float4*)&Apre[g][12];
        float v = a0.x*s[0] + a0.y*s[1] + a0.z*s[2] + a0.w*s[3]
                + a1.x*s[4] + a1.y*s[5] + a1.z*s[6] + a1.w*s[7]
                + a2.x*s[8] + a2.y*s[9] + a2.z*s[10] + a2.w*s[11]
                + a3.x*s[12] + a3.y*s[13] + a3.z*s[14] + a3.w*s[15];
        f16 vh = (f16)v;
        Srow[(long)g * HS + col] = vh;       // in-place: mixed scores
        float vr = (float)vh;                // stats from the rounded value
        float mn = fmaxf(m[g], vr);
        l[g] = l[g] * exp2f((m[g] - mn) * L2E) + exp2f((vr - mn) * L2E);
        m[g] = mn;
      }
    }
  }
  // butterfly reduce (m,l) across 64 lanes
  #pragma unroll
  for (int off = 32; off; off >>= 1){
    #pragma unroll
    for (int g = 0; g < 16; g++){
      float m2 = __shfl_xor(m[g], off);
      float l2 = __shfl_xor(l[g], off);
      float mn = fmaxf(m[g], m2);
      l[g] = l[g] * exp2f((m[g] - mn) * L2E) + l2 * exp2f((m2 - mn) * L2E);
      m[g] = mn;
    }
  }
  if (lane == 0){
    #pragma unroll
    for (int g = 0; g < 16; g++){ msh[wave][g] = m[g]; lsh[wave][g] = l[g]; }
  }
  __syncthreads();
  #pragma unroll
  for (int g = 0; g < 16; g++)
    m[g] = fmaxf(fmaxf(msh[0][g], msh[1][g]), fmaxf(msh[2][g], msh[3][g]));
  { // thread (gp = t>>4, g = t&15) builds Cpost[gp][g] = th_post*hs/l_g
    int gp = t >> 4, g = t & 15;
    float lf = 0.f;
    #pragma unroll
    for (int w = 0; w < 4; w++) lf += lsh[w][g] * exp2f((msh[w][g] - m[g]) * L2E);
    Cpost[gp][g] = th_post[gp * 16 + g] * hs[gp] * fin(1.f / lf);
  }
  __syncthreads();

  // sweep 2
  for (int it = 0; it < 9; it++){
    int col = it * 256 + t;
    if (col >= JP) continue;
    if (col < Jv){
      float e[16];
      #pragma unroll
      for (int g = 0; g < 16; g++){
        float v = (float)Srow[(long)g * HS + col];
        e[g] = exp2f(fminf(v - m[g], 0.f) * L2E);
      }
      #pragma unroll
      for (int gp = 0; gp < 16; gp++){
        float4 c0 = *(const float4*)&Cpost[gp][0];
        float4 c1 = *(const float4*)&Cpost[gp][4];
        float4 c2 = *(const float4*)&Cpost[gp][8];
        float4 c3 = *(const float4*)&Cpost[gp][12];
        float o = c0.x*e[0] + c0.y*e[1] + c0.z*e[2] + c0.w*e[3]
                + c1.x*e[4] + c1.y*e[5] + c1.z*e[6] + c1.w*e[7]
                + c2.x*e[8] + c2.y*e[9] + c2.z*e[10] + c2.w*e[11]
                + c3.x*e[12] + c3.y*e[13] + c3.z*e[14] + c3.w*e[15];
        Srow[(long)gp * HS + col] = (f16)o;
      }
    } else {
      #pragma unroll
      for (int gp = 0; gp < 16; gp++) Srow[(long)gp * HS + col] = (f16)0.f;
    }
  }
}

// ---------------- launch ----------------
extern "C" void kernel_launch(void* const* d_in, const int* in_sizes, int n_in,
                              void* d_out, int out_size, void* d_ws, size_t ws_size,
                              hipStream_t stream)
{
  (void)in_sizes; (void)n_in; (void)out_size; (void)ws_size;
  int* flag = (int*)d_ws;
  f16* ws   = (f16*)d_ws + 8;        // keep 16B alignment
  f16* xh   = ws;                    //  2,097,152
  f16* ctxh = xh   + 2097152;        //  8,388,608
  f16* wT   = ctxh + 8388608;        //  6,291,456 (wqT1,wkT1,wvT1,wqT2,wkT2,wvT2)
  f16* woT  = wT   + 6291456;        //  2,097,152 ([1024 x 2048])
  f16* qn   = woT  + 2097152;        //  2,097,152
  f16* kbuf = qn   + 2097152;        //  4,325,376
  f16* vt   = kbuf + 4325376;        //  4,325,376
  f16* av   = vt   + 4325376;        //  4,194,304 ([B*N x 2048])
  f16* tmp  = av   + 4194304;        //  4,194,304 (qp/kp/vp, reused sequentially)
  f16* Sc   = tmp  + 4194304;        //  8,650,752 (16 heads x IC x JP)
  f16* memc = Sc   + 8650752;        //  65,536 (mem_k1,mem_v1,mem_k2,mem_v2 canonical f16)
  float* parc = (float*)(memc + 65536); // 1088 f32: th_pre1,th_post1,th_pre2,th_post2,sc1,sc2,hs1,hs2
  // total ~93.5 MB

  // dtype probe on x
  detect_dtype<<<1, 64, 0, stream>>>(d_in[0], flag, 4096);

  // canonical conversions (dtype-dispatched, sanitized)
  cvt_any<<<1024, 256, 0, stream>>>(d_in[0], xh, 2097152, flag);
  cvt_any<<<2048, 256, 0, stream>>>(d_in[1], ctxh, 8388608, flag);
  for (int i = 0; i < 4; i++)  // mem_k1, mem_v1, mem_k2, mem_v2
    cvt_any<<<16, 256, 0, stream>>>(d_in[14 + i], memc + (long)i * 16384, 16384, flag);
  { // small params -> f32 pack
    const int  src[8] = {8, 9, 10, 11, 12, 13, 18, 19};
    const long off[8] = {0, 256, 512, 768, 1024, 1040, 1056, 1072};
    const long cnt[8] = {256, 256, 256, 256, 16, 16, 16, 16};
    for (int i = 0; i < 8; i++)
      cvt32_any<<<1, 256, 0, stream>>>(d_in[src[i]], parc + off[i], cnt[i], flag);
  }

  // transpose weights: wT[i][n][k] = w[k][n]
  for (int i = 0; i < 6; i++)
    transpose_any<<<dim3(32, 32), 256, 0, stream>>>(d_in[2 + i],
                                                    wT + (long)i * 1048576, 1024, 1024, flag);
  for (int L = 0; L < 2; L++)
    transpose_any<<<dim3(32, 32), 256, 0, stream>>>(d_in[20 + L],
                                                    woT + (long)L * 1024, 1024, 2048, flag);

  for (int L = 0; L < 2; L++){
    const f16* wqT = wT + (long)(3 * L + 0) * 1048576;
    const f16* wkT = wT + (long)(3 * L + 1) * 1048576;
    const f16* wvT = wT + (long)(3 * L + 2) * 1048576;
    const float* thpre  = parc + (long)L * 512;
    const float* thpost = parc + (long)L * 512 + 256;
    const float* scalep = parc + 1024 + (long)L * 16;
    const float* hsp    = parc + 1056 + (long)L * 16;
    const f16* mem_k = memc + (long)(2 * L) * 16384;
    const f16* mem_v = memc + (long)(2 * L + 1) * 16384;
    const f16* ctxL  = ctxh + (long)L * Bb * NCTXc * DIMd;

    // q = x @ wq   [2048 x 1024]
    gemm_bt<<<dim3(16, 32, 1), 256, 0, stream>>>(xh, wqT, tmp, 1024,
        1024, 1024, 1024, 0, 0, 0);
    qn_build<<<Bb * Nn, 256, 0, stream>>>(tmp, qn, scalep);

    // k = ctx @ wk  [4096 x 1024]
    gemm_bt<<<dim3(16, 64, 1), 256, 0, stream>>>(ctxL, wkT, tmp, 1024,
        1024, 1024, 1024, 0, 0, 0);
    kbuf_build<<<Bb * JP * Hh / 4, 256, 0, stream>>>(tmp, mem_k, kbuf);

    // v = ctx @ wv
    gemm_bt<<<dim3(16, 64, 1), 256, 0, stream>>>(ctxL, wvT, tmp, 1024,
        1024, 1024, 1024, 0, 0, 0);
    vt_build<<<Bb * Hh * (JP / 64), 256, 0, stream>>>(tmp, mem_v, vt);

    // attention in (b, i-chunk) pieces; S chunk = [h][IC][JP]
    for (int b = 0; b < Bb; b++){
      for (int c = 0; c < Nn / IC; c++){
        const f16* qc = qn + ((long)b * Nn + (long)c * IC) * 1024;
        const f16* kc = kbuf + (long)b * JP * 1024;
        // scores: per h: Sc[h][i][j] = qc[i, h*64:].kc[j, h*64:], K=64
        gemm_bt<<<dim3(JP / 64, IC / 64, Hh), 256, 0, stream>>>(qc, kc, Sc, 64,
            1024, 1024, JP, 64, 64, (long)IC * JP);
        // fused talking-heads softmax (in-place, pure VALU)
        softmax_mix_valu<<<IC, 256, 0, stream>>>(Sc, thpre, thpost, hsp);
        // out_h = attn @ v : per h: [IC x 64], K = JP
        gemm_bt<<<dim3(1, IC / 64, Hh), 256, 0, stream>>>(Sc,
            vt + (long)b * Hh * 64 * JP,
            av + ((long)b * Nn + (long)c * IC) * 2048 + (long)L * 1024, JP,
            JP, JP, 2048, (long)IC * JP, (long)64 * JP, 64);
      }
    }
  }

  // final: out = [av1|av2] @ [wo1;wo2]  => [2048 x 1024], K=2048 (dtype-dispatched store)
  gemm_bt_dyn<<<dim3(16, 32, 1), 256, 0, stream>>>(av, woT, d_out, 2048,
      2048, 2048, 1024, flag);
}

// Round 7
// 1561.220 us; speedup vs baseline: 1.6418x; 1.6418x over previous
//
#include <hip/hip_runtime.h>
#include <hip/hip_bf16.h>

// Problem constants
#define Bb    2
#define Nn    1024
#define NCTXc 2048
#define DIMd  1024
#define Hh    16
#define DHd   64
#define NMEM  16
#define Jv    (NMEM + NCTXc)   // 2064 valid kv rows
#define JP    2112             // padded to multiple of 64
#define HJP   (Hh * JP)        // 33792: row stride of S ([b][i][h][j])
#define L2E   1.44269504088896f

typedef _Float16 f16;
typedef _Float16 half8 __attribute__((ext_vector_type(8)));
typedef float    f32x4 __attribute__((ext_vector_type(4)));

__device__ __forceinline__ float bf2f(unsigned short u){
  union { unsigned int i; float f; } v; v.i = ((unsigned)u) << 16; return v.f;
}
// sanitize: NaN -> 0, clamp to f16-safe range (identity on well-formed inputs)
__device__ __forceinline__ float fin(float v){
  v = (v == v) ? v : 0.f;
  return fminf(fmaxf(v, -65504.f), 65504.f);
}
// dtype-flag-dispatched input read. isf32: 1 = buffer holds float32, 0 = bf16.
__device__ __forceinline__ float ldin(const void* p, long i, int isf32){
  return isf32 ? ((const float*)p)[i] : bf2f(((const unsigned short*)p)[i]);
}
__device__ __forceinline__ half8 h8zero(){
  half8 v;
  #pragma unroll
  for (int j = 0; j < 8; j++) v[j] = (f16)0.f;
  return v;
}

// ---------------- dtype probe ----------------
__global__ void detect_dtype(const void* __restrict__ p, int* __restrict__ flag, int n){
  const unsigned short* ub = (const unsigned short*)p;
  const float* fp = (const float*)p;
  int t = threadIdx.x;
  float bb = 0.f, bf = 0.f;
  for (int i = t; i < n; i += 64){
    float vb = bf2f(ub[i]);
    if (!(vb == vb) || fabsf(vb) > 1000.f) bb += 1.f;
    float vf = fp[i];
    if (!(vf == vf) || fabsf(vf) > 1000.f) bf += 1.f;
  }
  #pragma unroll
  for (int off = 32; off; off >>= 1){ bb += __shfl_xor(bb, off); bf += __shfl_xor(bf, off); }
  if (t == 0) *flag = (bf < bb) ? 1 : 0;
}

// ---------------- any-dtype -> f16 convert (sanitized) ----------------
__global__ __launch_bounds__(256) void cvt_any(const void* __restrict__ in, f16* __restrict__ out,
                                               long n, const int* __restrict__ flag){
  int isf = *flag;
  long stride = (long)gridDim.x * 256;
  for (long i = (long)blockIdx.x * 256 + threadIdx.x; i < n; i += stride)
    out[i] = (f16)fin(ldin(in, i, isf));
}

// ---------------- any-dtype -> f32 convert (sanitized, small params) ----------------
__global__ __launch_bounds__(256) void cvt32_any(const void* __restrict__ in, float* __restrict__ out,
                                                 long n, const int* __restrict__ flag){
  int isf = *flag;
  long stride = (long)gridDim.x * 256;
  for (long i = (long)blockIdx.x * 256 + threadIdx.x; i < n; i += stride)
    out[i] = fin(ldin(in, i, isf));
}

// ---------------- transpose + convert: out[c][r] = in[r][c] ----------------
__global__ __launch_bounds__(256) void transpose_any(const void* __restrict__ in,
                                                     f16* __restrict__ out,
                                                     int Cc, long ldo,
                                                     const int* __restrict__ flag){
  __shared__ f16 tile[32][33];
  int isf = *flag;
  int r0 = blockIdx.y * 32, c0 = blockIdx.x * 32;
  int tr = threadIdx.x >> 5, tc = threadIdx.x & 31;
  #pragma unroll
  for (int k = 0; k < 4; k++){
    int r = tr + k * 8;
    tile[r][tc] = (f16)fin(ldin(in, (long)(r0 + r) * Cc + c0 + tc, isf));
  }
  __syncthreads();
  #pragma unroll
  for (int k = 0; k < 4; k++){
    int r = tr + k * 8;
    out[(long)(c0 + r) * ldo + r0 + tc] = tile[tc][r];
  }
}

// ---------------- projection GEMM, raw A: C[m][n] = sum_k A[m][k]*Bt[n][k] ----------------
__global__ __launch_bounds__(256) void gemm_raw_bt(
    const void* __restrict__ A, const f16* __restrict__ Bt, f16* __restrict__ C,
    int K, long lda, long ldb, long ldc, long aOff, const int* __restrict__ flag)
{
  int isf = *flag;
  long m0 = (long)blockIdx.y * 64, n0 = (long)blockIdx.x * 64;

  __shared__ f16 As[64][40];
  __shared__ f16 Bs[64][40];
  int t = threadIdx.x;
  int wave = t >> 6, lane = t & 63;
  int wm = (wave >> 1) * 32, wn = (wave & 1) * 32;
  int fr = lane & 15, fq = lane >> 4;
  int srow = t >> 2, scol = (t & 3) * 8;

  f32x4 acc[2][2];
  #pragma unroll
  for (int a = 0; a < 2; a++)
    #pragma unroll
    for (int b = 0; b < 2; b++) acc[a][b] = (f32x4){0.f, 0.f, 0.f, 0.f};

  for (int k0 = 0; k0 < K; k0 += 32){
    long aidx = aOff + (m0 + srow) * lda + k0 + scol;
    half8 avv;
    if (isf){
      const float* ap = (const float*)A + aidx;
      float4 f0 = *(const float4*)ap;
      float4 f1 = *(const float4*)(ap + 4);
      avv[0] = (f16)fin(f0.x); avv[1] = (f16)fin(f0.y); avv[2] = (f16)fin(f0.z); avv[3] = (f16)fin(f0.w);
      avv[4] = (f16)fin(f1.x); avv[5] = (f16)fin(f1.y); avv[6] = (f16)fin(f1.z); avv[7] = (f16)fin(f1.w);
    } else {
      const unsigned short* up = (const unsigned short*)A + aidx;
      #pragma unroll
      for (int j = 0; j < 8; j++) avv[j] = (f16)fin(bf2f(up[j]));
    }
    half8 bvv = *(const half8*)(Bt + (n0 + srow) * ldb + k0 + scol);
    __syncthreads();
    *(half8*)&As[srow][scol] = avv;
    *(half8*)&Bs[srow][scol] = bvv;
    __syncthreads();
    #pragma unroll
    for (int ti = 0; ti < 2; ti++){
      half8 af = *(const half8*)&As[wm + 16 * ti + fr][fq * 8];
      #pragma unroll
      for (int tj = 0; tj < 2; tj++){
        half8 bf = *(const half8*)&Bs[wn + 16 * tj + fr][fq * 8];
        acc[ti][tj] = __builtin_amdgcn_mfma_f32_16x16x32_f16(af, bf, acc[ti][tj], 0, 0, 0);
      }
    }
  }
  #pragma unroll
  for (int ti = 0; ti < 2; ti++)
    #pragma unroll
    for (int tj = 0; tj < 2; tj++)
      #pragma unroll
      for (int r = 0; r < 4; r++){
        long row = m0 + wm + 16 * ti + fq * 4 + r;
        long col = n0 + wn + 16 * tj + fr;
        C[row * ldc + col] = (f16)acc[ti][tj][r];
      }
}

// ---------------- generic batched GEMM: C[m][n] = sum_k A[m][k]*Bt[n][k], z=(zb,zh) ----------------
__global__ __launch_bounds__(256) void gemm_bt(
    const f16* __restrict__ A, const f16* __restrict__ Bt, f16* __restrict__ C,
    int K, long lda, long ldb, long ldc,
    long sAb, long sBb, long sCb, long sAh, long sBh, long sCh, int nh)
{
  int z = blockIdx.z;
  int zb = z / nh, zh = z - zb * nh;
  A  += (long)zb * sAb + (long)zh * sAh;
  Bt += (long)zb * sBb + (long)zh * sBh;
  C  += (long)zb * sCb + (long)zh * sCh;
  long m0 = (long)blockIdx.y * 64, n0 = (long)blockIdx.x * 64;

  __shared__ f16 As[64][40];
  __shared__ f16 Bs[64][40];
  int t = threadIdx.x;
  int wave = t >> 6, lane = t & 63;
  int wm = (wave >> 1) * 32, wn = (wave & 1) * 32;
  int fr = lane & 15, fq = lane >> 4;
  int srow = t >> 2, scol = (t & 3) * 8;

  f32x4 acc[2][2];
  #pragma unroll
  for (int a = 0; a < 2; a++)
    #pragma unroll
    for (int b = 0; b < 2; b++) acc[a][b] = (f32x4){0.f, 0.f, 0.f, 0.f};

  for (int k0 = 0; k0 < K; k0 += 32){
    half8 avv = *(const half8*)(A  + (m0 + srow) * lda + k0 + scol);
    half8 bvv = *(const half8*)(Bt + (n0 + srow) * ldb + k0 + scol);
    __syncthreads();
    *(half8*)&As[srow][scol] = avv;
    *(half8*)&Bs[srow][scol] = bvv;
    __syncthreads();
    #pragma unroll
    for (int ti = 0; ti < 2; ti++){
      half8 af = *(const half8*)&As[wm + 16 * ti + fr][fq * 8];
      #pragma unroll
      for (int tj = 0; tj < 2; tj++){
        half8 bf = *(const half8*)&Bs[wn + 16 * tj + fr][fq * 8];
        acc[ti][tj] = __builtin_amdgcn_mfma_f32_16x16x32_f16(af, bf, acc[ti][tj], 0, 0, 0);
      }
    }
  }
  #pragma unroll
  for (int ti = 0; ti < 2; ti++)
    #pragma unroll
    for (int tj = 0; tj < 2; tj++)
      #pragma unroll
      for (int r = 0; r < 4; r++){
        long row = m0 + wm + 16 * ti + fq * 4 + r;
        long col = n0 + wn + 16 * tj + fr;
        C[row * ldc + col] = (f16)acc[ti][tj][r];
      }
}

// ---------------- final GEMM with dtype-dispatched output store ----------------
__global__ __launch_bounds__(256) void gemm_bt_dyn(
    const f16* __restrict__ A, const f16* __restrict__ Bt, void* __restrict__ C,
    int K, long lda, long ldb, long ldc, const int* __restrict__ flag)
{
  int isf = *flag;
  long m0 = (long)blockIdx.y * 64, n0 = (long)blockIdx.x * 64;

  __shared__ f16 As[64][40];
  __shared__ f16 Bs[64][40];
  int t = threadIdx.x;
  int wave = t >> 6, lane = t & 63;
  int wm = (wave >> 1) * 32, wn = (wave & 1) * 32;
  int fr = lane & 15, fq = lane >> 4;
  int srow = t >> 2, scol = (t & 3) * 8;

  f32x4 acc[2][2];
  #pragma unroll
  for (int a = 0; a < 2; a++)
    #pragma unroll
    for (int b = 0; b < 2; b++) acc[a][b] = (f32x4){0.f, 0.f, 0.f, 0.f};

  for (int k0 = 0; k0 < K; k0 += 32){
    half8 avv = *(const half8*)(A  + (m0 + srow) * lda + k0 + scol);
    half8 bvv = *(const half8*)(Bt + (n0 + srow) * ldb + k0 + scol);
    __syncthreads();
    *(half8*)&As[srow][scol] = avv;
    *(half8*)&Bs[srow][scol] = bvv;
    __syncthreads();
    #pragma unroll
    for (int ti = 0; ti < 2; ti++){
      half8 af = *(const half8*)&As[wm + 16 * ti + fr][fq * 8];
      #pragma unroll
      for (int tj = 0; tj < 2; tj++){
        half8 bf = *(const half8*)&Bs[wn + 16 * tj + fr][fq * 8];
        acc[ti][tj] = __builtin_amdgcn_mfma_f32_16x16x32_f16(af, bf, acc[ti][tj], 0, 0, 0);
      }
    }
  }
  #pragma unroll
  for (int ti = 0; ti < 2; ti++)
    #pragma unroll
    for (int tj = 0; tj < 2; tj++)
      #pragma unroll
      for (int r = 0; r < 4; r++){
        long row = m0 + wm + 16 * ti + fq * 4 + r;
        long col = n0 + wn + 16 * tj + fr;
        float v = acc[ti][tj][r];
        if (isf) ((float*)C)[row * ldc + col] = v;
        else     ((__hip_bfloat16*)C)[row * ldc + col] = __float2bfloat16(v);
      }
}

// ---------------- q: l2norm per head + fold per-head scale ----------------
__global__ __launch_bounds__(256) void qn_build(const f16* __restrict__ qp, f16* __restrict__ qn,
                                                const float* __restrict__ scale_p){
  int row = blockIdx.x;                 // 0..B*N-1
  int wave = threadIdx.x >> 6, lane = threadIdx.x & 63;
  #pragma unroll
  for (int hh = 0; hh < 4; hh++){
    int h = wave * 4 + hh;
    float v = (float)qp[(long)row * 1024 + h * 64 + lane];
    float ss = v * v;
    #pragma unroll
    for (int off = 32; off; off >>= 1) ss += __shfl_xor(ss, off);
    float sc = 1.0f / fmaxf(__expf(scale_p[h]), 0.01f);
    float o = v / fmaxf(sqrtf(ss), 1e-12f) * sc;
    qn[(long)row * 1024 + h * 64 + lane] = (f16)o;
  }
}

// ---------------- k buffer: mem_k prepended, l2norm, zero pad ----------------
__global__ __launch_bounds__(256) void kbuf_build(const f16* __restrict__ kp,
                                                  const f16* __restrict__ mem_k,
                                                  f16* __restrict__ kbuf){
  int id = blockIdx.x * 4 + (threadIdx.x >> 6);  // (b*JP + j)*16 + h
  int lane = threadIdx.x & 63;
  int h = id & 15; int bj = id >> 4; int j = bj % JP; int b = bj / JP;
  float v;
  if (j < NMEM)              v = (float)mem_k[(h * NMEM + j) * 64 + lane];
  else if (j < NMEM + NCTXc) v = (float)kp[((long)b * NCTXc + (j - NMEM)) * 1024 + h * 64 + lane];
  else                       v = 0.f;
  float ss = v * v;
  #pragma unroll
  for (int off = 32; off; off >>= 1) ss += __shfl_xor(ss, off);
  float o = v / fmaxf(sqrtf(ss), 1e-12f);
  kbuf[((long)b * JP + j) * 1024 + h * 64 + lane] = (f16)o;
}

// ---------------- v buffer, transposed per head: vt[(b,h)][d][j] ----------------
__global__ __launch_bounds__(256) void vt_build(const f16* __restrict__ vp,
                                                const f16* __restrict__ mem_v,
                                                f16* __restrict__ vt){
  __shared__ f16 tile[64][72];
  int id = blockIdx.x;
  int jt = id % (JP / 64); int h = (id / (JP / 64)) & 15; int b = id / (16 * (JP / 64));
  int j0 = jt * 64;
  int t = threadIdx.x;
  #pragma unroll
  for (int rep = 0; rep < 2; rep++){
    int idx = t + rep * 256;
    int jj = idx >> 3, c8 = (idx & 7) * 8;
    int j = j0 + jj;
    half8 v;
    if (j < NMEM){
      v = *(const half8*)(mem_v + (h * NMEM + j) * 64 + c8);
    } else if (j < NMEM + NCTXc){
      v = *(const half8*)(vp + ((long)b * NCTXc + (j - NMEM)) * 1024 + h * 64 + c8);
    } else {
      v = h8zero();
    }
    *(half8*)&tile[jj][c8] = v;
  }
  __syncthreads();
  #pragma unroll
  for (int rep = 0; rep < 2; rep++){
    int idx = t + rep * 256;
    int d = idx >> 3, j8 = (idx & 7) * 8;
    half8 o;
    #pragma unroll
    for (int k = 0; k < 8; k++) o[k] = tile[j8 + k][d];
    *(half8*)(vt + (((long)(b * 16 + h) * 64 + d) * JP) + j0 + j8) = o;
  }
}

// ---------------- fused pre-mix + softmax + post-mix, in-place, row-per-block ----------------
// S layout [b][i][h][j]: row base = (b*N+i)*HJP, head h at +h*JP (4.2 KB stride -> L2-local).
__global__ __launch_bounds__(256) void softmax_row(
    f16* __restrict__ S,
    const float* __restrict__ th_pre,
    const float* __restrict__ th_post,
    const float* __restrict__ hs)
{
  __shared__ float Apre[16][20];
  __shared__ float Cpost[16][20];
  __shared__ float msh[4][16], lsh[4][16];
  int t = threadIdx.x, wave = t >> 6, lane = t & 63;
  f16* Srow = S + (long)blockIdx.x * HJP;

  { int g = t >> 4, h = t & 15; Apre[g][h] = th_pre[g * 16 + h]; }
  __syncthreads();

  float m[16], l[16];
  #pragma unroll
  for (int g = 0; g < 16; g++){ m[g] = -1e30f; l[g] = 0.f; }

  // sweep 1: premix (in place) + online (m,l)
  for (int col = t; col < Jv; col += 256){
    float s[16];
    #pragma unroll
    for (int h = 0; h < 16; h++) s[h] = (float)Srow[h * JP + col];
    #pragma unroll
    for (int g = 0; g < 16; g++){
      float4 a0 = *(const float4*)&Apre[g][0];
      float4 a1 = *(const float4*)&Apre[g][4];
      float4 a2 = *(const float4*)&Apre[g][8];
      float4 a3 = *(const float4*)&Apre[g][12];
      float v = a0.x*s[0] + a0.y*s[1] + a0.z*s[2] + a0.w*s[3]
              + a1.x*s[4] + a1.y*s[5] + a1.z*s[6] + a1.w*s[7]
              + a2.x*s[8] + a2.y*s[9] + a2.z*s[10] + a2.w*s[11]
              + a3.x*s[12] + a3.y*s[13] + a3.z*s[14] + a3.w*s[15];
      f16 vh = (f16)v;
      Srow[g * JP + col] = vh;            // in-place: mixed scores
      float vr = (float)vh;               // stats from the rounded value
      float mn = fmaxf(m[g], vr);
      l[g] = l[g] * exp2f((m[g] - mn) * L2E) + exp2f((vr - mn) * L2E);
      m[g] = mn;
    }
  }
  // butterfly reduce (m,l) across 64 lanes
  #pragma unroll
  for (int off = 32; off; off >>= 1){
    #pragma unroll
    for (int g = 0; g < 16; g++){
      float m2 = __shfl_xor(m[g], off);
      float l2 = __shfl_xor(l[g], off);
      float mn = fmaxf(m[g], m2);
      l[g] = l[g] * exp2f((m[g] - mn) * L2E) + l2 * exp2f((m2 - mn) * L2E);
      m[g] = mn;
    }
  }
  if (lane == 0){
    #pragma unroll
    for (int g = 0; g < 16; g++){ msh[wave][g] = m[g]; lsh[wave][g] = l[g]; }
  }
  __syncthreads();
  #pragma unroll
  for (int g = 0; g < 16; g++)
    m[g] = fmaxf(fmaxf(msh[0][g], msh[1][g]), fmaxf(msh[2][g], msh[3][g]));
  { // thread (gp = t>>4, g = t&15) builds Cpost[gp][g] = th_post*hs/l_g
    int gp = t >> 4, g = t & 15;
    float lf = 0.f;
    #pragma unroll
    for (int w = 0; w < 4; w++) lf += lsh[w][g] * exp2f((msh[w][g] - m[g]) * L2E);
    Cpost[gp][g] = th_post[gp * 16 + g] * hs[gp] * fin(1.f / lf);
  }
  __syncthreads();

  // sweep 2: exp + postmix (in place), zero pad cols
  for (int col = t; col < JP; col += 256){
    if (col < Jv){
      float e[16];
      #pragma unroll
      for (int g = 0; g < 16; g++){
        float v = (float)Srow[g * JP + col];
        e[g] = exp2f(fminf(v - m[g], 0.f) * L2E);
      }
      #pragma unroll
      for (int gp = 0; gp < 16; gp++){
        float4 c0 = *(const float4*)&Cpost[gp][0];
        float4 c1 = *(const float4*)&Cpost[gp][4];
        float4 c2 = *(const float4*)&Cpost[gp][8];
        float4 c3 = *(const float4*)&Cpost[gp][12];
        float o = c0.x*e[0] + c0.y*e[1] + c0.z*e[2] + c0.w*e[3]
                + c1.x*e[4] + c1.y*e[5] + c1.z*e[6] + c1.w*e[7]
                + c2.x*e[8] + c2.y*e[9] + c2.z*e[10] + c2.w*e[11]
                + c3.x*e[12] + c3.y*e[13] + c3.z*e[14] + c3.w*e[15];
        Srow[gp * JP + col] = (f16)o;
      }
    } else {
      #pragma unroll
      for (int gp = 0; gp < 16; gp++) Srow[gp * JP + col] = (f16)0.f;
    }
  }
}

// ---------------- launch ----------------
extern "C" void kernel_launch(void* const* d_in, const int* in_sizes, int n_in,
                              void* d_out, int out_size, void* d_ws, size_t ws_size,
                              hipStream_t stream)
{
  (void)in_sizes; (void)n_in; (void)out_size; (void)ws_size;
  int* flag = (int*)d_ws;
  f16* ws   = (f16*)d_ws + 8;        // keep 16B alignment
  f16* wT   = ws;                    //  6,291,456 (wqT1,wkT1,wvT1,wqT2,wkT2,wvT2)
  f16* woT  = wT   + 6291456;        //  2,097,152 ([1024 x 2048])
  f16* qn   = woT  + 2097152;        //  2,097,152
  f16* kbuf = qn   + 2097152;        //  4,325,376
  f16* vt   = kbuf + 4325376;        //  4,325,376
  f16* av   = vt   + 4325376;        //  4,194,304 ([B*N x 2048])
  f16* memc = av   + 4194304;        //  65,536 (mem_k1,mem_v1,mem_k2,mem_v2)
  float* parc = (float*)(memc + 65536); // 1088 f32 (th_pre1,th_post1,th_pre2,th_post2,sc1,sc2,hs1,hs2)
  f16* S    = (f16*)(parc + 1088);   //  69,206,016 ([b][i][16][JP])
  f16* tmp  = S;                     //  aliases S head (dead before score GEMM writes S)
  // total ~185.0 MB

  // dtype probe on x
  detect_dtype<<<1, 64, 0, stream>>>(d_in[0], flag, 4096);

  for (int i = 0; i < 4; i++)  // mem_k1, mem_v1, mem_k2, mem_v2
    cvt_any<<<16, 256, 0, stream>>>(d_in[14 + i], memc + (long)i * 16384, 16384, flag);
  { // small params -> f32 pack
    const int  src[8] = {8, 9, 10, 11, 12, 13, 18, 19};
    const long off[8] = {0, 256, 512, 768, 1024, 1040, 1056, 1072};
    const long cnt[8] = {256, 256, 256, 256, 16, 16, 16, 16};
    for (int i = 0; i < 8; i++)
      cvt32_any<<<1, 256, 0, stream>>>(d_in[src[i]], parc + off[i], cnt[i], flag);
  }

  // transpose weights: wT[i][n][k] = w[k][n]
  for (int i = 0; i < 6; i++)
    transpose_any<<<dim3(32, 32), 256, 0, stream>>>(d_in[2 + i],
                                                    wT + (long)i * 1048576, 1024, 1024, flag);
  for (int L = 0; L < 2; L++)
    transpose_any<<<dim3(32, 32), 256, 0, stream>>>(d_in[20 + L],
                                                    woT + (long)L * 1024, 1024, 2048, flag);

  for (int L = 0; L < 2; L++){
    const f16* wqT = wT + (long)(3 * L + 0) * 1048576;
    const f16* wkT = wT + (long)(3 * L + 1) * 1048576;
    const f16* wvT = wT + (long)(3 * L + 2) * 1048576;
    const float* thpre  = parc + (long)L * 512;
    const float* thpost = parc + (long)L * 512 + 256;
    const float* scalep = parc + 1024 + (long)L * 16;
    const float* hsp    = parc + 1056 + (long)L * 16;
    const f16* mem_k = memc + (long)(2 * L) * 16384;
    const f16* mem_v = memc + (long)(2 * L + 1) * 16384;
    const long ctxOff = (long)L * Bb * NCTXc * DIMd;   // element offset into context

    // q = x @ wq   [2048 x 1024] (raw A)
    gemm_raw_bt<<<dim3(16, 32), 256, 0, stream>>>(d_in[0], wqT, tmp, 1024,
        1024, 1024, 1024, 0, flag);
    qn_build<<<Bb * Nn, 256, 0, stream>>>(tmp, qn, scalep);

    // k = ctx @ wk  [4096 x 1024] (raw A)
    gemm_raw_bt<<<dim3(16, 64), 256, 0, stream>>>(d_in[1], wkT, tmp, 1024,
        1024, 1024, 1024, ctxOff, flag);
    kbuf_build<<<Bb * JP * Hh / 4, 256, 0, stream>>>(tmp, mem_k, kbuf);

    // v = ctx @ wv (raw A)
    gemm_raw_bt<<<dim3(16, 64), 256, 0, stream>>>(d_in[1], wvT, tmp, 1024,
        1024, 1024, 1024, ctxOff, flag);
    vt_build<<<Bb * Hh * (JP / 64), 256, 0, stream>>>(tmp, mem_v, vt);

    // scores: per (b,h): S[b][i][h][j] = qn_h[b,i] . kbuf_h[b,j], K=64
    gemm_bt<<<dim3(JP / 64, Nn / 64, Bb * Hh), 256, 0, stream>>>(qn, kbuf, S, 64,
        1024, 1024, HJP,
        (long)Nn * 1024, (long)JP * 1024, (long)Nn * HJP,
        64, 64, JP, Hh);

    // fused talking-heads softmax (in-place), one block per (b,i) row
    softmax_row<<<Bb * Nn, 256, 0, stream>>>(S, thpre, thpost, hsp);

    // out_h = attn @ v : per (b,h): [1024 x 64], K = JP
    gemm_bt<<<dim3(1, Nn / 64, Bb * Hh), 256, 0, stream>>>(S, vt,
        av + (long)L * 1024, JP,
        HJP, JP, 2048,
        (long)Nn * HJP, (long)Hh * 64 * JP, (long)Nn * 2048,
        JP, (long)64 * JP, 64, Hh);

    // softmax grid note: 2048 blocks (~2 blocks/CU resident at 180 VGPR) vs 256 before
  }

  // final: out = [av1|av2] @ [wo1;wo2]  => [2048 x 1024], K=2048 (dtype-dispatched store)
  gemm_bt_dyn<<<dim3(16, 32), 256, 0, stream>>>(av, woT, d_out, 2048,
      2048, 2048, 1024, flag);
}